// Round 1
// baseline (5681.183 us; speedup 1.0000x reference)
//
#include <hip/hip_runtime.h>
#include <hip/hip_bf16.h>

#define N_NODES  100000
#define N_EDGES  1600000
#define HIDDEN   128
#define N_GRAPHS 2048

// ---------------------------------------------------------------------------
// k_zero: zero the y_hat region of d_out (it is poisoned 0xAA before each call)
// ---------------------------------------------------------------------------
__global__ void k_zero(float* __restrict__ out) {
    int i = blockIdx.x * blockDim.x + threadIdx.x;
    if (i < N_GRAPHS) out[i] = 0.0f;
}

// ---------------------------------------------------------------------------
// k_embed: A[n,:] = embed[x_idx[n],:]  ;  B[n,:] = (1+eps0) * A[n,:]
// one thread per (node, float4)
// ---------------------------------------------------------------------------
__global__ void k_embed(const int* __restrict__ idx,
                        const float* __restrict__ embed,
                        const float* __restrict__ eps,
                        float* __restrict__ A,
                        float* __restrict__ B) {
    int gid = blockIdx.x * blockDim.x + threadIdx.x;
    if (gid >= N_NODES * (HIDDEN / 4)) return;
    int n  = gid >> 5;          // /32
    int f4 = gid & 31;
    float s = 1.0f + eps[0];
    float4 v = reinterpret_cast<const float4*>(embed + (size_t)idx[n] * HIDDEN)[f4];
    reinterpret_cast<float4*>(A + (size_t)n * HIDDEN)[f4] = v;
    float4 w = make_float4(v.x * s, v.y * s, v.z * s, v.w * s);
    reinterpret_cast<float4*>(B + (size_t)n * HIDDEN)[f4] = w;
}

// ---------------------------------------------------------------------------
// k_scatter: AGG[dst,:] += X[src,:] over all edges.
// one thread per (edge, float4): gathers 16B, 4 atomic adds.
// ---------------------------------------------------------------------------
__global__ void k_scatter(const int* __restrict__ src,
                          const int* __restrict__ dst,
                          const float* __restrict__ X,
                          float* __restrict__ AGG) {
    int gid = blockIdx.x * blockDim.x + threadIdx.x;
    if (gid >= N_EDGES * (HIDDEN / 4)) return;
    int e  = gid >> 5;
    int f4 = gid & 31;
    int s = src[e];
    int d = dst[e];
    float4 v = reinterpret_cast<const float4*>(X + (size_t)s * HIDDEN)[f4];
    float* p = AGG + (size_t)d * HIDDEN + f4 * 4;
    atomicAdd(p + 0, v.x);
    atomicAdd(p + 1, v.y);
    atomicAdd(p + 2, v.z);
    atomicAdd(p + 3, v.w);
}

// ---------------------------------------------------------------------------
// k_gemm: Out = H @ W + bias, H:[nrows,128], W:[128,128].
// Tile: 64 rows x 128 cols per block of 256 threads.
// tx = tid&31 covers 4 cols, ty = tid>>5 covers 8 rows -> 32 acc per thread.
// K is chunked in 32s; H-chunk and W-chunk staged in LDS.
// IN-PLACE SAFE: all global reads of the 64-row H tile happen before the
// epilogue writes, and tiles are row-disjoint across blocks.
// RELU: apply relu to primary output. DUAL: also write (1+eps)*result to OutB.
// ---------------------------------------------------------------------------
template <bool RELU, bool DUAL>
__global__ __launch_bounds__(256) void k_gemm(const float* __restrict__ H,
                                              const float* __restrict__ W,
                                              const float* __restrict__ bias,
                                              const float* __restrict__ eps,
                                              float* __restrict__ OutA,
                                              float* __restrict__ OutB,
                                              int nrows) {
    __shared__ float Hs[64 * 36];   // row stride 36 (pad: keeps 16B align, 2-way bank max)
    __shared__ float Ws[32 * 128];  // k-chunk of W, row kk stride 128

    const int tid  = threadIdx.x;
    const int row0 = blockIdx.x * 64;
    const int tx   = tid & 31;   // col group: cols 4*tx .. 4*tx+3
    const int ty   = tid >> 5;   // row group: rows ty*8 .. ty*8+7

    float acc[8][4];
#pragma unroll
    for (int i = 0; i < 8; ++i)
#pragma unroll
        for (int j = 0; j < 4; ++j) acc[i][j] = 0.0f;

    for (int kc = 0; kc < HIDDEN; kc += 32) {
        // stage H tile chunk: 64 rows x 32 k = 512 float4, 2 per thread
#pragma unroll
        for (int it = 0; it < 2; ++it) {
            int idx = tid + it * 256;         // 0..511
            int r   = idx >> 3;               // 0..63
            int f4  = idx & 7;                // 0..7
            int row = row0 + r;
            float4 v = make_float4(0.f, 0.f, 0.f, 0.f);
            if (row < nrows)
                v = *reinterpret_cast<const float4*>(H + (size_t)row * HIDDEN + kc + f4 * 4);
            *reinterpret_cast<float4*>(&Hs[r * 36 + f4 * 4]) = v;
        }
        // stage W chunk: 32 x 128 = 1024 float4, 4 per thread
#pragma unroll
        for (int it = 0; it < 4; ++it) {
            int idx = tid + it * 256;         // 0..1023
            int kk  = idx >> 5;               // 0..31
            int f4  = idx & 31;               // 0..31
            *reinterpret_cast<float4*>(&Ws[kk * 128 + f4 * 4]) =
                *reinterpret_cast<const float4*>(W + (size_t)(kc + kk) * HIDDEN + f4 * 4);
        }
        __syncthreads();

#pragma unroll 8
        for (int kk = 0; kk < 32; ++kk) {
            float4 wv = *reinterpret_cast<const float4*>(&Ws[kk * 128 + tx * 4]);
#pragma unroll
            for (int i = 0; i < 8; ++i) {
                float h = Hs[(ty * 8 + i) * 36 + kk];
                acc[i][0] += h * wv.x;
                acc[i][1] += h * wv.y;
                acc[i][2] += h * wv.z;
                acc[i][3] += h * wv.w;
            }
        }
        __syncthreads();
    }

    // epilogue
    float4 bv = *reinterpret_cast<const float4*>(bias + tx * 4);
    float s = 1.0f;
    if (DUAL) s = 1.0f + eps[0];
#pragma unroll
    for (int i = 0; i < 8; ++i) {
        int row = row0 + ty * 8 + i;
        if (row < nrows) {
            float4 o;
            o.x = acc[i][0] + bv.x;
            o.y = acc[i][1] + bv.y;
            o.z = acc[i][2] + bv.z;
            o.w = acc[i][3] + bv.w;
            if (RELU) {
                o.x = fmaxf(o.x, 0.f); o.y = fmaxf(o.y, 0.f);
                o.z = fmaxf(o.z, 0.f); o.w = fmaxf(o.w, 0.f);
            }
            *reinterpret_cast<float4*>(OutA + (size_t)row * HIDDEN + tx * 4) = o;
            if (DUAL) {
                float4 o2 = make_float4(o.x * s, o.y * s, o.z * s, o.w * s);
                *reinterpret_cast<float4*>(OutB + (size_t)row * HIDDEN + tx * 4) = o2;
            }
        }
    }
}

// ---------------------------------------------------------------------------
// k_final: out_x[n] = dot(H[n,:], w2_1) + b2_1 ; y_hat[batch[n]] += out_x[n]
// one wave (64 lanes) per node.
// ---------------------------------------------------------------------------
__global__ void k_final(const float* __restrict__ H,
                        const float* __restrict__ w2,
                        const float* __restrict__ b2,
                        const int* __restrict__ batch,
                        float* __restrict__ out) {
    int gtid = blockIdx.x * blockDim.x + threadIdx.x;
    int n    = gtid >> 6;
    int lane = threadIdx.x & 63;
    if (n >= N_NODES) return;
    const float* h = H + (size_t)n * HIDDEN;
    float v = h[lane] * w2[lane] + h[lane + 64] * w2[lane + 64];
#pragma unroll
    for (int off = 32; off >= 1; off >>= 1) v += __shfl_xor(v, off, 64);
    if (lane == 0) {
        float r = v + b2[0];
        out[N_GRAPHS + n] = r;              // x output (return order: y_hat, x)
        atomicAdd(&out[batch[n]], r);       // y_hat segment sum
    }
}

// ---------------------------------------------------------------------------
extern "C" void kernel_launch(void* const* d_in, const int* in_sizes, int n_in,
                              void* d_out, int out_size, void* d_ws, size_t ws_size,
                              hipStream_t stream) {
    const int*   x_idx = (const int*)d_in[0];
    const int*   esrc  = (const int*)d_in[1];
    const int*   edst  = (const int*)d_in[2];
    const int*   batch = (const int*)d_in[3];
    const float* embed = (const float*)d_in[4];
    const float* eps0  = (const float*)d_in[5];
    const float* w1_0  = (const float*)d_in[6];
    const float* b1_0  = (const float*)d_in[7];
    const float* w2_0  = (const float*)d_in[8];
    const float* b2_0  = (const float*)d_in[9];
    const float* eps1  = (const float*)d_in[10];
    const float* w1_1  = (const float*)d_in[11];
    const float* b1_1  = (const float*)d_in[12];
    const float* w2_1  = (const float*)d_in[13];
    const float* b2_1  = (const float*)d_in[14];

    float* out = (float*)d_out;
    float* A = (float*)d_ws;                         // features x   [N,128]
    float* B = A + (size_t)N_NODES * HIDDEN;         // agg buffer   [N,128]

    const int nGemmBlocks    = (N_NODES + 63) / 64;                 // 1563
    const int nEmbedBlocks   = (N_NODES * 32 + 255) / 256;          // 12500
    const int nScatterBlocks = (N_EDGES * 32 + 255) / 256;          // 200000

    // y_hat := 0
    k_zero<<<(N_GRAPHS + 255) / 256, 256, 0, stream>>>(out);

    // x0 = embed[idx]; B = (1+eps0)*x0
    k_embed<<<nEmbedBlocks, 256, 0, stream>>>(x_idx, embed, eps0, A, B);

    // B += sum_{edges} x0[src]
    k_scatter<<<nScatterBlocks, 256, 0, stream>>>(esrc, edst, A, B);

    // B = B @ w1_0 + b1_0   (in place)
    k_gemm<false, false><<<nGemmBlocks, 256, 0, stream>>>(B, w1_0, b1_0, nullptr, B, nullptr, N_NODES);

    // A = relu(B @ w2_0 + b2_0);  B = (1+eps1)*A
    k_gemm<true, true><<<nGemmBlocks, 256, 0, stream>>>(B, w2_0, b2_0, eps1, A, B, N_NODES);

    // B += sum_{edges} A[src]
    k_scatter<<<nScatterBlocks, 256, 0, stream>>>(esrc, edst, A, B);

    // B = B @ w1_1 + b1_1   (in place)
    k_gemm<false, false><<<nGemmBlocks, 256, 0, stream>>>(B, w1_1, b1_1, nullptr, B, nullptr, N_NODES);

    // out_x = B @ w2_1 + b2_1 ; y_hat = segment_sum(out_x, batch)
    k_final<<<(N_NODES * 64 + 255) / 256, 256, 0, stream>>>(B, w2_1, b2_1, batch, out);
}

// Round 2
// 759.436 us; speedup vs baseline: 7.4808x; 7.4808x over previous
//
#include <hip/hip_runtime.h>
#include <hip/hip_bf16.h>

#define N_NODES  100000
#define N_EDGES  1600000
#define HIDDEN   128
#define N_GRAPHS 2048
#define SCAN_CHUNK 1024   // elements per scan block (256 thr x 4)
#define N_SCAN_BLOCKS ((N_NODES + SCAN_CHUNK - 1) / SCAN_CHUNK)   // 98

// ---------------------------------------------------------------------------
// k_zero_f / k_zero_i: init (buffers are poisoned 0xAA before every call)
// ---------------------------------------------------------------------------
__global__ void k_zero_f(float* __restrict__ p, int n) {
    int i = blockIdx.x * blockDim.x + threadIdx.x;
    if (i < n) p[i] = 0.0f;
}
__global__ void k_zero_i(int* __restrict__ p, int n) {
    int i = blockIdx.x * blockDim.x + threadIdx.x;
    if (i < n) p[i] = 0;
}

// ---------------------------------------------------------------------------
// k_embed: A[n,:] = embed[x_idx[n],:]
// ---------------------------------------------------------------------------
__global__ void k_embed(const int* __restrict__ idx,
                        const float* __restrict__ embed,
                        float* __restrict__ A) {
    int gid = blockIdx.x * blockDim.x + threadIdx.x;
    if (gid >= N_NODES * (HIDDEN / 4)) return;
    int n  = gid >> 5;
    int f4 = gid & 31;
    float4 v = reinterpret_cast<const float4*>(embed + (size_t)idx[n] * HIDDEN)[f4];
    reinterpret_cast<float4*>(A + (size_t)n * HIDDEN)[f4] = v;
}

// ---------------------------------------------------------------------------
// CSR build: histogram -> exclusive scan (2-level) -> permute
// ---------------------------------------------------------------------------
__global__ void k_hist(const int* __restrict__ dst, int* __restrict__ deg) {
    int e = blockIdx.x * blockDim.x + threadIdx.x;
    if (e < N_EDGES) atomicAdd(&deg[dst[e]], 1);
}

// per-block exclusive scan of deg -> rowptr, block totals -> bsum
__global__ __launch_bounds__(256) void k_scan1(const int* __restrict__ deg,
                                               int* __restrict__ rowptr,
                                               int* __restrict__ bsum) {
    __shared__ int sh[256];
    int base = blockIdx.x * SCAN_CHUNK;
    int t = threadIdx.x;
    int v[4]; int s = 0;
#pragma unroll
    for (int j = 0; j < 4; ++j) {
        int i = base + t * 4 + j;
        v[j] = (i < N_NODES) ? deg[i] : 0;
        s += v[j];
    }
    sh[t] = s;
    __syncthreads();
    for (int off = 1; off < 256; off <<= 1) {
        int x = (t >= off) ? sh[t - off] : 0;
        __syncthreads();
        sh[t] += x;
        __syncthreads();
    }
    if (t == 255) bsum[blockIdx.x] = sh[255];
    int run = sh[t] - s;   // exclusive prefix of this thread within block
#pragma unroll
    for (int j = 0; j < 4; ++j) {
        int i = base + t * 4 + j;
        if (i < N_NODES) rowptr[i] = run;
        run += v[j];
    }
}

// single-block exclusive scan of block sums (nb <= 128)
__global__ void k_scan2(int* __restrict__ bsum, int nb) {
    __shared__ int sh[128];
    int t = threadIdx.x;
    int v = (t < nb) ? bsum[t] : 0;
    sh[t] = v;
    __syncthreads();
    for (int off = 1; off < 128; off <<= 1) {
        int x = (t >= off) ? sh[t - off] : 0;
        __syncthreads();
        sh[t] += x;
        __syncthreads();
    }
    if (t < nb) bsum[t] = sh[t] - v;   // exclusive
}

// add block offsets; also init cursor = rowptr and rowptr[N] = E
__global__ void k_scan3(int* __restrict__ rowptr, const int* __restrict__ bsum,
                        int* __restrict__ cursor) {
    int i = blockIdx.x * blockDim.x + threadIdx.x;
    if (i < N_NODES) {
        int r = rowptr[i] + bsum[i / SCAN_CHUNK];
        rowptr[i] = r;
        cursor[i] = r;
    }
    if (i == 0) rowptr[N_NODES] = N_EDGES;
}

__global__ void k_permute(const int* __restrict__ src, const int* __restrict__ dst,
                          int* __restrict__ cursor, int* __restrict__ csr) {
    int e = blockIdx.x * blockDim.x + threadIdx.x;
    if (e < N_EDGES) {
        int p = atomicAdd(&cursor[dst[e]], 1);
        csr[p] = src[e];
    }
}

// ---------------------------------------------------------------------------
// k_agg: B[n,:] = (1+eps)*X[n,:] + sum_{p in [rowptr[n],rowptr[n+1])} X[csr[p],:]
// one wave (64 lanes) per node; lane covers feats {lane, lane+64}.
// ---------------------------------------------------------------------------
__global__ __launch_bounds__(256) void k_agg(const float* __restrict__ X,
                                             const int* __restrict__ rowptr,
                                             const int* __restrict__ csr,
                                             const float* __restrict__ eps,
                                             float* __restrict__ B) {
    int gtid = blockIdx.x * blockDim.x + threadIdx.x;
    int n    = gtid >> 6;
    int lane = threadIdx.x & 63;
    if (n >= N_NODES) return;
    float s = 1.0f + eps[0];
    const float* xr = X + (size_t)n * HIDDEN;
    float a0 = s * xr[lane];
    float a1 = s * xr[lane + 64];
    int p   = rowptr[n];
    int end = rowptr[n + 1];
    for (; p + 4 <= end; p += 4) {
        int s0 = csr[p], s1 = csr[p + 1], s2 = csr[p + 2], s3 = csr[p + 3];
        const float* r0 = X + (size_t)s0 * HIDDEN;
        const float* r1 = X + (size_t)s1 * HIDDEN;
        const float* r2 = X + (size_t)s2 * HIDDEN;
        const float* r3 = X + (size_t)s3 * HIDDEN;
        float v00 = r0[lane], v01 = r0[lane + 64];
        float v10 = r1[lane], v11 = r1[lane + 64];
        float v20 = r2[lane], v21 = r2[lane + 64];
        float v30 = r3[lane], v31 = r3[lane + 64];
        a0 += (v00 + v10) + (v20 + v30);
        a1 += (v01 + v11) + (v21 + v31);
    }
    for (; p < end; ++p) {
        const float* r = X + (size_t)csr[p] * HIDDEN;
        a0 += r[lane];
        a1 += r[lane + 64];
    }
    float* br = B + (size_t)n * HIDDEN;
    br[lane]      = a0;
    br[lane + 64] = a1;
}

// ---------------------------------------------------------------------------
// k_gemm: Out = H @ W + bias, H:[nrows,128], W:[128,128].
// 64 rows x 128 cols per block of 256 threads; in-place safe (row-disjoint
// tiles; all H reads of a tile precede its epilogue writes).
// ---------------------------------------------------------------------------
template <bool RELU>
__global__ __launch_bounds__(256) void k_gemm(const float* __restrict__ H,
                                              const float* __restrict__ W,
                                              const float* __restrict__ bias,
                                              float* __restrict__ Out,
                                              int nrows) {
    __shared__ float Hs[64 * 36];
    __shared__ float Ws[32 * 128];

    const int tid  = threadIdx.x;
    const int row0 = blockIdx.x * 64;
    const int tx   = tid & 31;
    const int ty   = tid >> 5;

    float acc[8][4];
#pragma unroll
    for (int i = 0; i < 8; ++i)
#pragma unroll
        for (int j = 0; j < 4; ++j) acc[i][j] = 0.0f;

    for (int kc = 0; kc < HIDDEN; kc += 32) {
#pragma unroll
        for (int it = 0; it < 2; ++it) {
            int idx = tid + it * 256;
            int r   = idx >> 3;
            int f4  = idx & 7;
            int row = row0 + r;
            float4 v = make_float4(0.f, 0.f, 0.f, 0.f);
            if (row < nrows)
                v = *reinterpret_cast<const float4*>(H + (size_t)row * HIDDEN + kc + f4 * 4);
            *reinterpret_cast<float4*>(&Hs[r * 36 + f4 * 4]) = v;
        }
#pragma unroll
        for (int it = 0; it < 4; ++it) {
            int idx = tid + it * 256;
            int kk  = idx >> 5;
            int f4  = idx & 31;
            *reinterpret_cast<float4*>(&Ws[kk * 128 + f4 * 4]) =
                *reinterpret_cast<const float4*>(W + (size_t)(kc + kk) * HIDDEN + f4 * 4);
        }
        __syncthreads();

#pragma unroll 8
        for (int kk = 0; kk < 32; ++kk) {
            float4 wv = *reinterpret_cast<const float4*>(&Ws[kk * 128 + tx * 4]);
#pragma unroll
            for (int i = 0; i < 8; ++i) {
                float h = Hs[(ty * 8 + i) * 36 + kk];
                acc[i][0] += h * wv.x;
                acc[i][1] += h * wv.y;
                acc[i][2] += h * wv.z;
                acc[i][3] += h * wv.w;
            }
        }
        __syncthreads();
    }

    float4 bv = *reinterpret_cast<const float4*>(bias + tx * 4);
#pragma unroll
    for (int i = 0; i < 8; ++i) {
        int row = row0 + ty * 8 + i;
        if (row < nrows) {
            float4 o;
            o.x = acc[i][0] + bv.x;
            o.y = acc[i][1] + bv.y;
            o.z = acc[i][2] + bv.z;
            o.w = acc[i][3] + bv.w;
            if (RELU) {
                o.x = fmaxf(o.x, 0.f); o.y = fmaxf(o.y, 0.f);
                o.z = fmaxf(o.z, 0.f); o.w = fmaxf(o.w, 0.f);
            }
            *reinterpret_cast<float4*>(Out + (size_t)row * HIDDEN + tx * 4) = o;
        }
    }
}

// ---------------------------------------------------------------------------
// k_final: out_x[n] = dot(H[n,:], w2_1) + b2_1 ; y_hat[batch[n]] += out_x[n]
// ---------------------------------------------------------------------------
__global__ void k_final(const float* __restrict__ H,
                        const float* __restrict__ w2,
                        const float* __restrict__ b2,
                        const int* __restrict__ batch,
                        float* __restrict__ out) {
    int gtid = blockIdx.x * blockDim.x + threadIdx.x;
    int n    = gtid >> 6;
    int lane = threadIdx.x & 63;
    if (n >= N_NODES) return;
    const float* h = H + (size_t)n * HIDDEN;
    float v = h[lane] * w2[lane] + h[lane + 64] * w2[lane + 64];
#pragma unroll
    for (int off = 32; off >= 1; off >>= 1) v += __shfl_xor(v, off, 64);
    if (lane == 0) {
        float r = v + b2[0];
        out[N_GRAPHS + n] = r;
        atomicAdd(&out[batch[n]], r);
    }
}

// ---------------------------------------------------------------------------
extern "C" void kernel_launch(void* const* d_in, const int* in_sizes, int n_in,
                              void* d_out, int out_size, void* d_ws, size_t ws_size,
                              hipStream_t stream) {
    const int*   x_idx = (const int*)d_in[0];
    const int*   esrc  = (const int*)d_in[1];
    const int*   edst  = (const int*)d_in[2];
    const int*   batch = (const int*)d_in[3];
    const float* embed = (const float*)d_in[4];
    const float* eps0  = (const float*)d_in[5];
    const float* w1_0  = (const float*)d_in[6];
    const float* b1_0  = (const float*)d_in[7];
    const float* w2_0  = (const float*)d_in[8];
    const float* b2_0  = (const float*)d_in[9];
    const float* eps1  = (const float*)d_in[10];
    const float* w1_1  = (const float*)d_in[11];
    const float* b1_1  = (const float*)d_in[12];
    const float* w2_1  = (const float*)d_in[13];
    const float* b2_1  = (const float*)d_in[14];

    float* out = (float*)d_out;

    // workspace layout
    float* A      = (float*)d_ws;                          // [N,128]
    float* B      = A + (size_t)N_NODES * HIDDEN;          // [N,128]
    int*   rowptr = (int*)(B + (size_t)N_NODES * HIDDEN);  // N+1
    int*   cursor = rowptr + (N_NODES + 1);                // N (also deg)
    int*   csr    = cursor + N_NODES;                      // E
    int*   bsum   = csr + N_EDGES;                         // 128

    int* deg = cursor;   // reuse: deg consumed by scan1 before cursor written

    const int nGemmBlocks  = (N_NODES + 63) / 64;
    const int nEmbedBlocks = (N_NODES * 32 + 255) / 256;
    const int nEdgeBlocks  = (N_EDGES + 255) / 256;
    const int nWaveBlocks  = (N_NODES * 64 + 255) / 256;   // 1 wave per node

    // init
    k_zero_f<<<(N_GRAPHS + 255) / 256, 256, 0, stream>>>(out, N_GRAPHS);
    k_zero_i<<<(N_NODES + 255) / 256, 256, 0, stream>>>(deg, N_NODES);

    // x0 = embed[idx]
    k_embed<<<nEmbedBlocks, 256, 0, stream>>>(x_idx, embed, A);

    // CSR build (in-edges)
    k_hist<<<nEdgeBlocks, 256, 0, stream>>>(edst, deg);
    k_scan1<<<N_SCAN_BLOCKS, 256, 0, stream>>>(deg, rowptr, bsum);
    k_scan2<<<1, 128, 0, stream>>>(bsum, N_SCAN_BLOCKS);
    k_scan3<<<(N_NODES + 255) / 256, 256, 0, stream>>>(rowptr, bsum, cursor);
    k_permute<<<nEdgeBlocks, 256, 0, stream>>>(esrc, edst, cursor, csr);

    // layer 0
    k_agg<<<nWaveBlocks, 256, 0, stream>>>(A, rowptr, csr, eps0, B);
    k_gemm<false><<<nGemmBlocks, 256, 0, stream>>>(B, w1_0, b1_0, B, N_NODES);
    k_gemm<true><<<nGemmBlocks, 256, 0, stream>>>(B, w2_0, b2_0, A, N_NODES);

    // layer 1
    k_agg<<<nWaveBlocks, 256, 0, stream>>>(A, rowptr, csr, eps1, B);
    k_gemm<false><<<nGemmBlocks, 256, 0, stream>>>(B, w1_1, b1_1, B, N_NODES);

    // out_x = B @ w2_1 + b2_1 ; y_hat = segment_sum(out_x, batch)
    k_final<<<nWaveBlocks, 256, 0, stream>>>(B, w2_1, b2_1, batch, out);
}

// Round 3
// 464.047 us; speedup vs baseline: 12.2427x; 1.6365x over previous
//
#include <hip/hip_runtime.h>
#include <hip/hip_bf16.h>

#define N_NODES  100000
#define N_EDGES  1600000
#define HIDDEN   128
#define N_GRAPHS 2048
#define SCAN_CHUNK 1024   // elements per scan block (256 thr x 4)
#define N_SCAN_BLOCKS ((N_NODES + SCAN_CHUNK - 1) / SCAN_CHUNK)   // 98

__device__ __forceinline__ float bf2f(unsigned short h) {
    return __uint_as_float(((unsigned)h) << 16);
}
__device__ __forceinline__ unsigned short f2bf(float f) {   // round-to-nearest-even
    unsigned u = __float_as_uint(f);
    unsigned r = (u + 0x7FFFu + ((u >> 16) & 1u)) >> 16;
    return (unsigned short)r;
}

// ---------------------------------------------------------------------------
// init kernels (d_out / d_ws poisoned 0xAA before every call)
// ---------------------------------------------------------------------------
__global__ void k_zero_f(float* __restrict__ p, int n) {
    int i = blockIdx.x * blockDim.x + threadIdx.x;
    if (i < n) p[i] = 0.0f;
}
__global__ void k_zero_i(int* __restrict__ p, int n) {
    int i = blockIdx.x * blockDim.x + threadIdx.x;
    if (i < n) p[i] = 0;
}

// ---------------------------------------------------------------------------
// k_prep: fold each layer's two linears into one.
//   blocks 0..63 : Wc0 = w1_0 @ w2_0                       [128,128]
//   block 64     : t<128  : bc0[t] = b1_0 @ w2_0[:,t] + b2_0[t]
//                  t>=128 : wc1[t-128] = w1_1[t-128,:] @ w2_1
//                  t==0   : bc1 = b1_1 @ w2_1 + b2_1
// ---------------------------------------------------------------------------
__global__ __launch_bounds__(256) void k_prep(const float* __restrict__ w1_0,
                                              const float* __restrict__ w2_0,
                                              const float* __restrict__ b1_0,
                                              const float* __restrict__ b2_0,
                                              const float* __restrict__ w1_1,
                                              const float* __restrict__ b1_1,
                                              const float* __restrict__ w2_1,
                                              const float* __restrict__ b2_1,
                                              float* __restrict__ Wc0,
                                              float* __restrict__ bc0,
                                              float* __restrict__ wc1,
                                              float* __restrict__ bc1) {
    int t = threadIdx.x;
    if (blockIdx.x < 64) {
        int g = blockIdx.x * 256 + t;      // 0..16383
        int i = g >> 7, j = g & 127;
        float s = 0.f;
#pragma unroll 8
        for (int k = 0; k < HIDDEN; ++k)
            s += w1_0[i * HIDDEN + k] * w2_0[k * HIDDEN + j];
        Wc0[g] = s;
    } else {
        if (t < 128) {
            float s = 0.f;
#pragma unroll 8
            for (int k = 0; k < HIDDEN; ++k)
                s += b1_0[k] * w2_0[k * HIDDEN + t];
            bc0[t] = s + b2_0[t];
            if (t == 0) {
                float q = 0.f;
                for (int k = 0; k < HIDDEN; ++k) q += b1_1[k] * w2_1[k];
                bc1[0] = q + b2_1[0];
            }
        } else {
            int i = t - 128;
            float s = 0.f;
#pragma unroll 8
            for (int k = 0; k < HIDDEN; ++k)
                s += w1_1[i * HIDDEN + k] * w2_1[k];
            wc1[i] = s;
        }
    }
}

// ---------------------------------------------------------------------------
// CSR build: histogram(+rank) -> exclusive scan (2-level) -> atomic-free scatter
// ---------------------------------------------------------------------------
__global__ void k_hist_rank(const int* __restrict__ dst,
                            int* __restrict__ deg, int* __restrict__ rank) {
    int e = blockIdx.x * blockDim.x + threadIdx.x;
    if (e < N_EDGES) rank[e] = atomicAdd(&deg[dst[e]], 1);
}

__global__ __launch_bounds__(256) void k_scan1(const int* __restrict__ deg,
                                               int* __restrict__ rowptr,
                                               int* __restrict__ bsum) {
    __shared__ int sh[256];
    int base = blockIdx.x * SCAN_CHUNK;
    int t = threadIdx.x;
    int v[4]; int s = 0;
#pragma unroll
    for (int j = 0; j < 4; ++j) {
        int i = base + t * 4 + j;
        v[j] = (i < N_NODES) ? deg[i] : 0;
        s += v[j];
    }
    sh[t] = s;
    __syncthreads();
    for (int off = 1; off < 256; off <<= 1) {
        int x = (t >= off) ? sh[t - off] : 0;
        __syncthreads();
        sh[t] += x;
        __syncthreads();
    }
    if (t == 255) bsum[blockIdx.x] = sh[255];
    int run = sh[t] - s;
#pragma unroll
    for (int j = 0; j < 4; ++j) {
        int i = base + t * 4 + j;
        if (i < N_NODES) rowptr[i] = run;
        run += v[j];
    }
}

__global__ void k_scan2(int* __restrict__ bsum, int nb) {
    __shared__ int sh[128];
    int t = threadIdx.x;
    int v = (t < nb) ? bsum[t] : 0;
    sh[t] = v;
    __syncthreads();
    for (int off = 1; off < 128; off <<= 1) {
        int x = (t >= off) ? sh[t - off] : 0;
        __syncthreads();
        sh[t] += x;
        __syncthreads();
    }
    if (t < nb) bsum[t] = sh[t] - v;
}

__global__ void k_scan3(int* __restrict__ rowptr, const int* __restrict__ bsum) {
    int i = blockIdx.x * blockDim.x + threadIdx.x;
    if (i < N_NODES) rowptr[i] += bsum[i / SCAN_CHUNK];
    if (i == 0) rowptr[N_NODES] = N_EDGES;
}

// scatter without atomics: position = rowptr[dst] + rank. payload: src node id
// AND its vocab index (for the L1-table layer-0 gather).
__global__ void k_csr(const int* __restrict__ src, const int* __restrict__ dst,
                      const int* __restrict__ rank, const int* __restrict__ rowptr,
                      const int* __restrict__ x_idx,
                      int* __restrict__ csr_src, int* __restrict__ csr_vix) {
    int e = blockIdx.x * blockDim.x + threadIdx.x;
    if (e < N_EDGES) {
        int s = src[e];
        int p = rowptr[dst[e]] + rank[e];
        csr_src[p] = s;
        csr_vix[p] = x_idx[s];
    }
}

// ---------------------------------------------------------------------------
// k_agg0: B[n,:] = (1+eps0)*embed[x_idx[n],:] + sum_p embed[csr_vix[p],:]
// embed table is 14 KB -> L1-resident. one wave per node, lane covers
// feats {lane, lane+64}.
// ---------------------------------------------------------------------------
__global__ __launch_bounds__(256) void k_agg0(const int* __restrict__ x_idx,
                                              const float* __restrict__ embed,
                                              const int* __restrict__ rowptr,
                                              const int* __restrict__ csr_vix,
                                              const float* __restrict__ eps,
                                              float* __restrict__ B) {
    int gtid = blockIdx.x * blockDim.x + threadIdx.x;
    int n    = gtid >> 6;
    int lane = threadIdx.x & 63;
    if (n >= N_NODES) return;
    float s = 1.0f + eps[0];
    const float* er = embed + (size_t)x_idx[n] * HIDDEN;
    float a0 = s * er[lane];
    float a1 = s * er[lane + 64];
    int p   = rowptr[n];
    int end = rowptr[n + 1];
    for (; p + 4 <= end; p += 4) {
        int v0 = csr_vix[p], v1 = csr_vix[p + 1], v2 = csr_vix[p + 2], v3 = csr_vix[p + 3];
        const float* r0 = embed + (size_t)v0 * HIDDEN;
        const float* r1 = embed + (size_t)v1 * HIDDEN;
        const float* r2 = embed + (size_t)v2 * HIDDEN;
        const float* r3 = embed + (size_t)v3 * HIDDEN;
        a0 += (r0[lane] + r1[lane]) + (r2[lane] + r3[lane]);
        a1 += (r0[lane + 64] + r1[lane + 64]) + (r2[lane + 64] + r3[lane + 64]);
    }
    for (; p < end; ++p) {
        const float* r = embed + (size_t)csr_vix[p] * HIDDEN;
        a0 += r[lane];
        a1 += r[lane + 64];
    }
    float* br = B + (size_t)n * HIDDEN;
    br[lane]      = a0;
    br[lane + 64] = a1;
}

// ---------------------------------------------------------------------------
// k_gemm: Abf = bf16(relu(B @ Wc0 + bc0)), B:[N,128] fp32, Wc0:[128,128].
// 64 rows x 128 cols per block of 256 threads.
// ---------------------------------------------------------------------------
__global__ __launch_bounds__(256) void k_gemm(const float* __restrict__ H,
                                              const float* __restrict__ W,
                                              const float* __restrict__ bias,
                                              unsigned short* __restrict__ Abf) {
    __shared__ float Hs[64 * 36];
    __shared__ float Ws[32 * 128];

    const int tid  = threadIdx.x;
    const int row0 = blockIdx.x * 64;
    const int tx   = tid & 31;
    const int ty   = tid >> 5;

    float acc[8][4];
#pragma unroll
    for (int i = 0; i < 8; ++i)
#pragma unroll
        for (int j = 0; j < 4; ++j) acc[i][j] = 0.0f;

    for (int kc = 0; kc < HIDDEN; kc += 32) {
#pragma unroll
        for (int it = 0; it < 2; ++it) {
            int idx = tid + it * 256;
            int r   = idx >> 3;
            int f4  = idx & 7;
            int row = row0 + r;
            float4 v = make_float4(0.f, 0.f, 0.f, 0.f);
            if (row < N_NODES)
                v = *reinterpret_cast<const float4*>(H + (size_t)row * HIDDEN + kc + f4 * 4);
            *reinterpret_cast<float4*>(&Hs[r * 36 + f4 * 4]) = v;
        }
#pragma unroll
        for (int it = 0; it < 4; ++it) {
            int idx = tid + it * 256;
            int kk  = idx >> 5;
            int f4  = idx & 31;
            *reinterpret_cast<float4*>(&Ws[kk * 128 + f4 * 4]) =
                *reinterpret_cast<const float4*>(W + (size_t)(kc + kk) * HIDDEN + f4 * 4);
        }
        __syncthreads();

#pragma unroll 8
        for (int kk = 0; kk < 32; ++kk) {
            float4 wv = *reinterpret_cast<const float4*>(&Ws[kk * 128 + tx * 4]);
#pragma unroll
            for (int i = 0; i < 8; ++i) {
                float h = Hs[(ty * 8 + i) * 36 + kk];
                acc[i][0] += h * wv.x;
                acc[i][1] += h * wv.y;
                acc[i][2] += h * wv.z;
                acc[i][3] += h * wv.w;
            }
        }
        __syncthreads();
    }

    float4 bv = *reinterpret_cast<const float4*>(bias + tx * 4);
#pragma unroll
    for (int i = 0; i < 8; ++i) {
        int row = row0 + ty * 8 + i;
        if (row < N_NODES) {
            ushort4 o;
            o.x = f2bf(fmaxf(acc[i][0] + bv.x, 0.f));
            o.y = f2bf(fmaxf(acc[i][1] + bv.y, 0.f));
            o.z = f2bf(fmaxf(acc[i][2] + bv.z, 0.f));
            o.w = f2bf(fmaxf(acc[i][3] + bv.w, 0.f));
            *reinterpret_cast<ushort4*>(Abf + (size_t)row * HIDDEN + tx * 4) = o;
        }
    }
}

// ---------------------------------------------------------------------------
// k_agg1: B[n,:] = (1+eps1)*x1[n,:] + sum_p x1[csr_src[p],:], x1 stored bf16.
// one wave per node, lane covers feats {2*lane, 2*lane+1} (ushort2 = 4B/lane).
// ---------------------------------------------------------------------------
__global__ __launch_bounds__(256) void k_agg1(const unsigned short* __restrict__ Abf,
                                              const int* __restrict__ rowptr,
                                              const int* __restrict__ csr_src,
                                              const float* __restrict__ eps,
                                              float* __restrict__ B) {
    int gtid = blockIdx.x * blockDim.x + threadIdx.x;
    int n    = gtid >> 6;
    int lane = threadIdx.x & 63;
    if (n >= N_NODES) return;
    float s = 1.0f + eps[0];
    ushort2 u = reinterpret_cast<const ushort2*>(Abf + (size_t)n * HIDDEN)[lane];
    float a0 = s * bf2f(u.x);
    float a1 = s * bf2f(u.y);
    int p   = rowptr[n];
    int end = rowptr[n + 1];
    for (; p + 4 <= end; p += 4) {
        int s0 = csr_src[p], s1 = csr_src[p + 1], s2 = csr_src[p + 2], s3 = csr_src[p + 3];
        ushort2 u0 = reinterpret_cast<const ushort2*>(Abf + (size_t)s0 * HIDDEN)[lane];
        ushort2 u1 = reinterpret_cast<const ushort2*>(Abf + (size_t)s1 * HIDDEN)[lane];
        ushort2 u2 = reinterpret_cast<const ushort2*>(Abf + (size_t)s2 * HIDDEN)[lane];
        ushort2 u3 = reinterpret_cast<const ushort2*>(Abf + (size_t)s3 * HIDDEN)[lane];
        a0 += (bf2f(u0.x) + bf2f(u1.x)) + (bf2f(u2.x) + bf2f(u3.x));
        a1 += (bf2f(u0.y) + bf2f(u1.y)) + (bf2f(u2.y) + bf2f(u3.y));
    }
    for (; p < end; ++p) {
        ushort2 uu = reinterpret_cast<const ushort2*>(Abf + (size_t)csr_src[p] * HIDDEN)[lane];
        a0 += bf2f(uu.x);
        a1 += bf2f(uu.y);
    }
    reinterpret_cast<float2*>(B + (size_t)n * HIDDEN)[lane] = make_float2(a0, a1);
}

// ---------------------------------------------------------------------------
// k_final: r = dot(B[n,:], wc1) + bc1 ; x_out[n] = r ; y_hat[batch[n]] += r
// ---------------------------------------------------------------------------
__global__ void k_final(const float* __restrict__ H,
                        const float* __restrict__ wc1,
                        const float* __restrict__ bc1,
                        const int* __restrict__ batch,
                        float* __restrict__ out) {
    int gtid = blockIdx.x * blockDim.x + threadIdx.x;
    int n    = gtid >> 6;
    int lane = threadIdx.x & 63;
    if (n >= N_NODES) return;
    const float* h = H + (size_t)n * HIDDEN;
    float v = h[lane] * wc1[lane] + h[lane + 64] * wc1[lane + 64];
#pragma unroll
    for (int off = 32; off >= 1; off >>= 1) v += __shfl_xor(v, off, 64);
    if (lane == 0) {
        float r = v + bc1[0];
        out[N_GRAPHS + n] = r;
        atomicAdd(&out[batch[n]], r);
    }
}

// ---------------------------------------------------------------------------
extern "C" void kernel_launch(void* const* d_in, const int* in_sizes, int n_in,
                              void* d_out, int out_size, void* d_ws, size_t ws_size,
                              hipStream_t stream) {
    const int*   x_idx = (const int*)d_in[0];
    const int*   esrc  = (const int*)d_in[1];
    const int*   edst  = (const int*)d_in[2];
    const int*   batch = (const int*)d_in[3];
    const float* embed = (const float*)d_in[4];
    const float* eps0  = (const float*)d_in[5];
    const float* w1_0  = (const float*)d_in[6];
    const float* b1_0  = (const float*)d_in[7];
    const float* w2_0  = (const float*)d_in[8];
    const float* b2_0  = (const float*)d_in[9];
    const float* eps1  = (const float*)d_in[10];
    const float* w1_1  = (const float*)d_in[11];
    const float* b1_1  = (const float*)d_in[12];
    const float* w2_1  = (const float*)d_in[13];
    const float* b2_1  = (const float*)d_in[14];

    float* out = (float*)d_out;

    // workspace layout
    float*          B       = (float*)d_ws;                         // [N,128] fp32
    unsigned short* Abf     = (unsigned short*)(B + (size_t)N_NODES * HIDDEN); // [N,128] bf16
    float*          Wc0     = (float*)(Abf + (size_t)N_NODES * HIDDEN);        // [128,128]
    float*          bc0     = Wc0 + HIDDEN * HIDDEN;                // 128
    float*          wc1     = bc0 + HIDDEN;                         // 128
    float*          bc1     = wc1 + HIDDEN;                         // 1
    int*            rowptr  = (int*)(bc1 + 1);                      // N+1
    int*            deg     = rowptr + (N_NODES + 1);               // N
    int*            rank    = deg + N_NODES;                        // E
    int*            csr_src = rank + N_EDGES;                       // E
    int*            csr_vix = csr_src + N_EDGES;                    // E
    int*            bsum    = csr_vix + N_EDGES;                    // 128

    const int nGemmBlocks = (N_NODES + 63) / 64;
    const int nEdgeBlocks = (N_EDGES + 255) / 256;
    const int nWaveBlocks = (N_NODES * 64 + 255) / 256;

    k_zero_f<<<(N_GRAPHS + 255) / 256, 256, 0, stream>>>(out, N_GRAPHS);
    k_zero_i<<<(N_NODES + 255) / 256, 256, 0, stream>>>(deg, N_NODES);
    k_prep<<<65, 256, 0, stream>>>(w1_0, w2_0, b1_0, b2_0, w1_1, b1_1, w2_1, b2_1,
                                   Wc0, bc0, wc1, bc1);

    // CSR build (in-edges), atomic-free scatter
    k_hist_rank<<<nEdgeBlocks, 256, 0, stream>>>(edst, deg, rank);
    k_scan1<<<N_SCAN_BLOCKS, 256, 0, stream>>>(deg, rowptr, bsum);
    k_scan2<<<1, 128, 0, stream>>>(bsum, N_SCAN_BLOCKS);
    k_scan3<<<(N_NODES + 255) / 256, 256, 0, stream>>>(rowptr, bsum);
    k_csr<<<nEdgeBlocks, 256, 0, stream>>>(esrc, edst, rank, rowptr, x_idx, csr_src, csr_vix);

    // layer 0: agg from L1-resident embed table, then single fused GEMM
    k_agg0<<<nWaveBlocks, 256, 0, stream>>>(x_idx, embed, rowptr, csr_vix, eps0, B);
    k_gemm<<<nGemmBlocks, 256, 0, stream>>>(B, Wc0, bc0, Abf);

    // layer 1: agg over bf16 x1, then fused 128-dot + segment sum
    k_agg1<<<nWaveBlocks, 256, 0, stream>>>(Abf, rowptr, csr_src, eps1, B);
    k_final<<<nWaveBlocks, 256, 0, stream>>>(B, wc1, bc1, batch, out);
}

// Round 4
// 325.370 us; speedup vs baseline: 17.4607x; 1.4262x over previous
//
#include <hip/hip_runtime.h>

#define N_NODES  100000
#define N_EDGES  1600000
#define HIDDEN   128
#define N_GRAPHS 2048
#define VOCAB    28

// ---------------------------------------------------------------------------
// init kernels (d_out / d_ws poisoned 0xAA before every call)
// ---------------------------------------------------------------------------
__global__ void k_zero_f(float* __restrict__ p, int n) {
    int i = blockIdx.x * blockDim.x + threadIdx.x;
    if (i < n) p[i] = 0.0f;
}
__global__ void k_zero_i4(int4* __restrict__ p, int n4) {
    int i = blockIdx.x * blockDim.x + threadIdx.x;
    if (i < n4) p[i] = make_int4(0, 0, 0, 0);
}

// ---------------------------------------------------------------------------
// k_prep: fold each layer's two linears into one.
//   blocks 0..63 : Wc0 = w1_0 @ w2_0                       [128,128]
//   block 64     : t<128  : bc0[t] = b1_0 @ w2_0[:,t] + b2_0[t]
//                  t>=128 : wc1[t-128] = w1_1[t-128,:] @ w2_1
//                  t==0   : bc1 = b1_1 @ w2_1 + b2_1
// ---------------------------------------------------------------------------
__global__ __launch_bounds__(256) void k_prep(const float* __restrict__ w1_0,
                                              const float* __restrict__ w2_0,
                                              const float* __restrict__ b1_0,
                                              const float* __restrict__ b2_0,
                                              const float* __restrict__ w1_1,
                                              const float* __restrict__ b1_1,
                                              const float* __restrict__ w2_1,
                                              const float* __restrict__ b2_1,
                                              float* __restrict__ Wc0,
                                              float* __restrict__ bc0,
                                              float* __restrict__ wc1,
                                              float* __restrict__ bc1) {
    int t = threadIdx.x;
    if (blockIdx.x < 64) {
        int g = blockIdx.x * 256 + t;      // 0..16383
        int i = g >> 7, j = g & 127;
        float s = 0.f;
#pragma unroll 8
        for (int k = 0; k < HIDDEN; ++k)
            s += w1_0[i * HIDDEN + k] * w2_0[k * HIDDEN + j];
        Wc0[g] = s;
    } else {
        if (t < 128) {
            float s = 0.f;
#pragma unroll 8
            for (int k = 0; k < HIDDEN; ++k)
                s += b1_0[k] * w2_0[k * HIDDEN + t];
            bc0[t] = s + b2_0[t];
            if (t == 0) {
                float q = 0.f;
                for (int k = 0; k < HIDDEN; ++k) q += b1_1[k] * w2_1[k];
                bc1[0] = q + b2_1[0];
            }
        } else {
            int i = t - 128;
            float s = 0.f;
#pragma unroll 8
            for (int k = 0; k < HIDDEN; ++k)
                s += w1_1[i * HIDDEN + k] * w2_1[k];
            wc1[i] = s;
        }
    }
}

// ---------------------------------------------------------------------------
// k_prep2: EW = embed @ Wc0   [28,128]  (14 KB table)
// ---------------------------------------------------------------------------
__global__ __launch_bounds__(256) void k_prep2(const float* __restrict__ embed,
                                               const float* __restrict__ Wc0,
                                               float* __restrict__ EW) {
    int g = blockIdx.x * 256 + threadIdx.x;
    if (g >= VOCAB * HIDDEN) return;
    int i = g >> 7, j = g & 127;
    float s = 0.f;
#pragma unroll 8
    for (int k = 0; k < HIDDEN; ++k)
        s += embed[i * HIDDEN + k] * Wc0[k * HIDDEN + j];
    EW[g] = s;
}

// ---------------------------------------------------------------------------
// k_count: counts[dst][x_idx[src]] += 1 over all edges (int atomics, low
// contention: 1.6M atomics over 2.8M cells).
// ---------------------------------------------------------------------------
__global__ void k_count(const int* __restrict__ esrc, const int* __restrict__ edst,
                        const int* __restrict__ x_idx, int* __restrict__ counts) {
    int e = blockIdx.x * blockDim.x + threadIdx.x;
    if (e < N_EDGES)
        atomicAdd(&counts[(size_t)edst[e] * VOCAB + x_idx[esrc[e]]], 1);
}

// ---------------------------------------------------------------------------
// k_layer0: per node n (one wave):
//   acc = (1+eps0)*EW[x_idx[n]] + sum_v counts[n][v]*EW[v] + bc0
//   d[n] = dot(relu(acc), wc1)
// EW/bc0/wc1 staged in LDS (15 KB). Lane covers feats {lane, lane+64}.
// counts row: 28 ints = 7 aligned int4 uniform loads (28*4=112 B, 16|112n).
// ---------------------------------------------------------------------------
__global__ __launch_bounds__(256) void k_layer0(const int* __restrict__ x_idx,
                                                const int* __restrict__ counts,
                                                const float* __restrict__ EW,
                                                const float* __restrict__ bc0,
                                                const float* __restrict__ wc1,
                                                const float* __restrict__ eps0,
                                                float* __restrict__ d) {
    __shared__ float ew[VOCAB * HIDDEN];
    __shared__ float sbc0[HIDDEN];
    __shared__ float swc1[HIDDEN];
    for (int i = threadIdx.x; i < VOCAB * HIDDEN; i += 256) ew[i] = EW[i];
    for (int i = threadIdx.x; i < HIDDEN; i += 256) { sbc0[i] = bc0[i]; swc1[i] = wc1[i]; }
    __syncthreads();

    int gtid = blockIdx.x * blockDim.x + threadIdx.x;
    int n    = gtid >> 6;
    int lane = threadIdx.x & 63;
    if (n >= N_NODES) return;

    float s = 1.0f + eps0[0];
    int xi = x_idx[n];
    float a0 = s * ew[xi * HIDDEN + lane];
    float a1 = s * ew[xi * HIDDEN + lane + 64];

    const int4* cp = reinterpret_cast<const int4*>(counts + (size_t)n * VOCAB);
    int4 c[7];
#pragma unroll
    for (int q = 0; q < 7; ++q) c[q] = cp[q];

#define TERM(cc, v)                                             \
    if (cc) {                                                   \
        float f = (float)(cc);                                  \
        a0 += f * ew[(v) * HIDDEN + lane];                      \
        a1 += f * ew[(v) * HIDDEN + lane + 64];                 \
    }
    TERM(c[0].x, 0)  TERM(c[0].y, 1)  TERM(c[0].z, 2)  TERM(c[0].w, 3)
    TERM(c[1].x, 4)  TERM(c[1].y, 5)  TERM(c[1].z, 6)  TERM(c[1].w, 7)
    TERM(c[2].x, 8)  TERM(c[2].y, 9)  TERM(c[2].z, 10) TERM(c[2].w, 11)
    TERM(c[3].x, 12) TERM(c[3].y, 13) TERM(c[3].z, 14) TERM(c[3].w, 15)
    TERM(c[4].x, 16) TERM(c[4].y, 17) TERM(c[4].z, 18) TERM(c[4].w, 19)
    TERM(c[5].x, 20) TERM(c[5].y, 21) TERM(c[5].z, 22) TERM(c[5].w, 23)
    TERM(c[6].x, 24) TERM(c[6].y, 25) TERM(c[6].z, 26) TERM(c[6].w, 27)
#undef TERM

    a0 = fmaxf(a0 + sbc0[lane], 0.f);
    a1 = fmaxf(a1 + sbc0[lane + 64], 0.f);
    float t = a0 * swc1[lane] + a1 * swc1[lane + 64];
#pragma unroll
    for (int off = 32; off >= 1; off >>= 1) t += __shfl_xor(t, off, 64);
    if (lane == 0) d[n] = t;
}

// ---------------------------------------------------------------------------
// k_dscatter: racc[dst] += d[src] over all edges (scalar float atomics,
// d is 400 KB -> L2-resident).
// ---------------------------------------------------------------------------
__global__ void k_dscatter(const int* __restrict__ esrc, const int* __restrict__ edst,
                           const float* __restrict__ d, float* __restrict__ racc) {
    int e = blockIdx.x * blockDim.x + threadIdx.x;
    if (e < N_EDGES)
        atomicAdd(&racc[edst[e]], d[esrc[e]]);
}

// ---------------------------------------------------------------------------
// k_out: r = (1+eps1)*d[n] + racc[n] + bc1 ; x_out[n] = r ;
// y_hat segment-sum via LDS (batch is sorted -> block spans few graphs).
// ---------------------------------------------------------------------------
__global__ __launch_bounds__(256) void k_out(const float* __restrict__ d,
                                             const float* __restrict__ racc,
                                             const int* __restrict__ batch,
                                             const float* __restrict__ eps1,
                                             const float* __restrict__ bc1,
                                             float* __restrict__ out) {
    __shared__ float acc[N_GRAPHS];
    int n0 = blockIdx.x * 256;
    int n  = n0 + threadIdx.x;
    int nlast = min(n0 + 255, N_NODES - 1);
    int g0 = batch[n0];
    int g1 = batch[nlast];
    for (int i = g0 + threadIdx.x; i <= g1; i += 256) acc[i] = 0.f;
    __syncthreads();
    if (n < N_NODES) {
        float r = (1.0f + eps1[0]) * d[n] + racc[n] + bc1[0];
        out[N_GRAPHS + n] = r;
        atomicAdd(&acc[batch[n]], r);
    }
    __syncthreads();
    for (int i = g0 + threadIdx.x; i <= g1; i += 256) {
        float v = acc[i];
        if (v != 0.f) atomicAdd(&out[i], v);
    }
}

// ---------------------------------------------------------------------------
extern "C" void kernel_launch(void* const* d_in, const int* in_sizes, int n_in,
                              void* d_out, int out_size, void* d_ws, size_t ws_size,
                              hipStream_t stream) {
    const int*   x_idx = (const int*)d_in[0];
    const int*   esrc  = (const int*)d_in[1];
    const int*   edst  = (const int*)d_in[2];
    const int*   batch = (const int*)d_in[3];
    const float* embed = (const float*)d_in[4];
    const float* eps0  = (const float*)d_in[5];
    const float* w1_0  = (const float*)d_in[6];
    const float* b1_0  = (const float*)d_in[7];
    const float* w2_0  = (const float*)d_in[8];
    const float* b2_0  = (const float*)d_in[9];
    const float* eps1  = (const float*)d_in[10];
    const float* w1_1  = (const float*)d_in[11];
    const float* b1_1  = (const float*)d_in[12];
    const float* w2_1  = (const float*)d_in[13];
    const float* b2_1  = (const float*)d_in[14];

    float* out = (float*)d_out;

    // workspace layout: [counts | racc | d | Wc0 | bc0 | wc1 | bc1 | EW]
    int*   counts = (int*)d_ws;                                  // N*28 ints
    float* racc   = (float*)(counts + (size_t)N_NODES * VOCAB);  // N
    float* d      = racc + N_NODES;                              // N
    float* Wc0    = d + N_NODES;                                 // 128*128
    float* bc0    = Wc0 + HIDDEN * HIDDEN;                       // 128
    float* wc1    = bc0 + HIDDEN;                                // 128
    float* bc1    = wc1 + HIDDEN;                                // 1
    float* EW     = bc1 + 1;                                     // 28*128

    const int nEdgeBlocks = (N_EDGES + 255) / 256;               // 6250
    const int nWaveBlocks = (N_NODES * 64 + 255) / 256;          // 25000
    const int nOutBlocks  = (N_NODES + 255) / 256;               // 391

    // zero y_hat and counts+racc (contiguous: N*28 + N ints = 2,900,000; /4 exact)
    k_zero_f<<<(N_GRAPHS + 255) / 256, 256, 0, stream>>>(out, N_GRAPHS);
    {
        int n4 = (N_NODES * VOCAB + N_NODES) / 4;                // 725000
        k_zero_i4<<<(n4 + 255) / 256, 256, 0, stream>>>((int4*)counts, n4);
    }

    // fold weights: Wc0, bc0, wc1, bc1 ; then EW = embed @ Wc0
    k_prep<<<65, 256, 0, stream>>>(w1_0, w2_0, b1_0, b2_0, w1_1, b1_1, w2_1, b2_1,
                                   Wc0, bc0, wc1, bc1);
    k_prep2<<<(VOCAB * HIDDEN + 255) / 256, 256, 0, stream>>>(embed, Wc0, EW);

    // neighbor vocab histogram per node
    k_count<<<nEdgeBlocks, 256, 0, stream>>>(esrc, edst, x_idx, counts);

    // layer 0 + dot(wc1): d[n]
    k_layer0<<<nWaveBlocks, 256, 0, stream>>>(x_idx, counts, EW, bc0, wc1, eps0, d);

    // layer 1 aggregation in scalar space
    k_dscatter<<<nEdgeBlocks, 256, 0, stream>>>(esrc, edst, d, racc);

    // outputs: x and y_hat
    k_out<<<nOutBlocks, 256, 0, stream>>>(d, racc, batch, eps1, bc1, out);
}

// Round 5
// 293.322 us; speedup vs baseline: 19.3684x; 1.1093x over previous
//
#include <hip/hip_runtime.h>

#define N_NODES  100000
#define N_EDGES  1600000
#define HIDDEN   128
#define N_GRAPHS 2048
#define VOCAB    28
#define NCOPY    8      // racc privatization factor (≈ one per XCD)
#define NPW      16     // nodes per wave in k_layer0

// ---------------------------------------------------------------------------
// init kernels (d_out / d_ws poisoned 0xAA before every call)
// ---------------------------------------------------------------------------
__global__ void k_zero_f(float* __restrict__ p, int n) {
    int i = blockIdx.x * blockDim.x + threadIdx.x;
    if (i < n) p[i] = 0.0f;
}
__global__ void k_zero_i4(int4* __restrict__ p, int n4) {
    int i = blockIdx.x * blockDim.x + threadIdx.x;
    if (i < n4) p[i] = make_int4(0, 0, 0, 0);
}

// ---------------------------------------------------------------------------
// k_prep: fold each layer's two linears into one.
//   blocks 0..63 : Wc0 = w1_0 @ w2_0                       [128,128]
//   block 64     : t<128  : bc0[t] = b1_0 @ w2_0[:,t] + b2_0[t]
//                  t>=128 : wc1[t-128] = w1_1[t-128,:] @ w2_1
//                  t==0   : bc1 = b1_1 @ w2_1 + b2_1
// ---------------------------------------------------------------------------
__global__ __launch_bounds__(256) void k_prep(const float* __restrict__ w1_0,
                                              const float* __restrict__ w2_0,
                                              const float* __restrict__ b1_0,
                                              const float* __restrict__ b2_0,
                                              const float* __restrict__ w1_1,
                                              const float* __restrict__ b1_1,
                                              const float* __restrict__ w2_1,
                                              const float* __restrict__ b2_1,
                                              float* __restrict__ Wc0,
                                              float* __restrict__ bc0,
                                              float* __restrict__ wc1,
                                              float* __restrict__ bc1) {
    int t = threadIdx.x;
    if (blockIdx.x < 64) {
        int g = blockIdx.x * 256 + t;      // 0..16383
        int i = g >> 7, j = g & 127;
        float s = 0.f;
#pragma unroll 8
        for (int k = 0; k < HIDDEN; ++k)
            s += w1_0[i * HIDDEN + k] * w2_0[k * HIDDEN + j];
        Wc0[g] = s;
    } else {
        if (t < 128) {
            float s = 0.f;
#pragma unroll 8
            for (int k = 0; k < HIDDEN; ++k)
                s += b1_0[k] * w2_0[k * HIDDEN + t];
            bc0[t] = s + b2_0[t];
            if (t == 0) {
                float q = 0.f;
                for (int k = 0; k < HIDDEN; ++k) q += b1_1[k] * w2_1[k];
                bc1[0] = q + b2_1[0];
            }
        } else {
            int i = t - 128;
            float s = 0.f;
#pragma unroll 8
            for (int k = 0; k < HIDDEN; ++k)
                s += w1_1[i * HIDDEN + k] * w2_1[k];
            wc1[i] = s;
        }
    }
}

// ---------------------------------------------------------------------------
// k_prep2: EW = embed @ Wc0   [28,128]  (14 KB table)
// ---------------------------------------------------------------------------
__global__ __launch_bounds__(256) void k_prep2(const float* __restrict__ embed,
                                               const float* __restrict__ Wc0,
                                               float* __restrict__ EW) {
    int g = blockIdx.x * 256 + threadIdx.x;
    if (g >= VOCAB * HIDDEN) return;
    int i = g >> 7, j = g & 127;
    float s = 0.f;
#pragma unroll 8
    for (int k = 0; k < HIDDEN; ++k)
        s += embed[i * HIDDEN + k] * Wc0[k * HIDDEN + j];
    EW[g] = s;
}

// ---------------------------------------------------------------------------
// k_count: counts[dst][x_idx[src]] += 1 over all edges.
// ---------------------------------------------------------------------------
__global__ void k_count(const int* __restrict__ esrc, const int* __restrict__ edst,
                        const int* __restrict__ x_idx, int* __restrict__ counts) {
    int e = blockIdx.x * blockDim.x + threadIdx.x;
    if (e < N_EDGES)
        atomicAdd(&counts[(size_t)edst[e] * VOCAB + x_idx[esrc[e]]], 1);
}

// ---------------------------------------------------------------------------
// k_layer0: per node n:
//   acc = (1+eps0)*EW[x_idx[n]] + sum_v counts[n][v]*EW[v] + bc0
//   d[n] = dot(relu(acc), wc1)
// One wave handles NPW consecutive nodes; EW/bc0/wc1 staged once per block.
// Lane covers feats {lane, lane+64}. counts row loads are wave-uniform.
// ---------------------------------------------------------------------------
__global__ __launch_bounds__(256) void k_layer0(const int* __restrict__ x_idx,
                                                const int* __restrict__ counts,
                                                const float* __restrict__ EW,
                                                const float* __restrict__ bc0,
                                                const float* __restrict__ wc1,
                                                const float* __restrict__ eps0,
                                                float* __restrict__ d) {
    __shared__ float ew[VOCAB * HIDDEN];
    __shared__ float sbc0[HIDDEN];
    __shared__ float swc1[HIDDEN];
    for (int i = threadIdx.x; i < VOCAB * HIDDEN; i += 256) ew[i] = EW[i];
    for (int i = threadIdx.x; i < HIDDEN; i += 256) { sbc0[i] = bc0[i]; swc1[i] = wc1[i]; }
    __syncthreads();

    int wave = blockIdx.x * 4 + (threadIdx.x >> 6);
    int lane = threadIdx.x & 63;
    float s = 1.0f + eps0[0];
    float wlo = swc1[lane], whi = swc1[lane + 64];
    float blo = sbc0[lane], bhi = sbc0[lane + 64];

    int nbase = wave * NPW;
#pragma unroll 1
    for (int i = 0; i < NPW; ++i) {
        int n = nbase + i;
        if (n >= N_NODES) return;

        int xi = x_idx[n];
        float a0 = s * ew[xi * HIDDEN + lane];
        float a1 = s * ew[xi * HIDDEN + lane + 64];

        const int4* cp = reinterpret_cast<const int4*>(counts + (size_t)n * VOCAB);
        int4 c[7];
#pragma unroll
        for (int q = 0; q < 7; ++q) c[q] = cp[q];

#define TERM(cc, v)                                             \
        if (cc) {                                               \
            float f = (float)(cc);                              \
            a0 += f * ew[(v) * HIDDEN + lane];                  \
            a1 += f * ew[(v) * HIDDEN + lane + 64];             \
        }
        TERM(c[0].x, 0)  TERM(c[0].y, 1)  TERM(c[0].z, 2)  TERM(c[0].w, 3)
        TERM(c[1].x, 4)  TERM(c[1].y, 5)  TERM(c[1].z, 6)  TERM(c[1].w, 7)
        TERM(c[2].x, 8)  TERM(c[2].y, 9)  TERM(c[2].z, 10) TERM(c[2].w, 11)
        TERM(c[3].x, 12) TERM(c[3].y, 13) TERM(c[3].z, 14) TERM(c[3].w, 15)
        TERM(c[4].x, 16) TERM(c[4].y, 17) TERM(c[4].z, 18) TERM(c[4].w, 19)
        TERM(c[5].x, 20) TERM(c[5].y, 21) TERM(c[5].z, 22) TERM(c[5].w, 23)
        TERM(c[6].x, 24) TERM(c[6].y, 25) TERM(c[6].z, 26) TERM(c[6].w, 27)
#undef TERM

        a0 = fmaxf(a0 + blo, 0.f);
        a1 = fmaxf(a1 + bhi, 0.f);
        float t = a0 * wlo + a1 * whi;
#pragma unroll
        for (int off = 32; off >= 1; off >>= 1) t += __shfl_xor(t, off, 64);
        if (lane == 0) d[n] = t;
    }
}

// ---------------------------------------------------------------------------
// k_dscatter: racc8[blockIdx%8][dst] += d[src]. Blocks round-robin across
// XCDs, so each copy's lines stay (mostly) in one XCD's L2 -> no cross-XCD
// line bouncing; per-line contention /8. Correct for ANY blockIdx->XCD map.
// ---------------------------------------------------------------------------
__global__ void k_dscatter(const int* __restrict__ esrc, const int* __restrict__ edst,
                           const float* __restrict__ d, float* __restrict__ racc8) {
    int e = blockIdx.x * blockDim.x + threadIdx.x;
    if (e < N_EDGES) {
        float* racc = racc8 + (size_t)(blockIdx.x & (NCOPY - 1)) * N_NODES;
        atomicAdd(&racc[edst[e]], d[esrc[e]]);
    }
}

// ---------------------------------------------------------------------------
// k_out: r = (1+eps1)*d[n] + sum_c racc8[c][n] + bc1 ; x_out[n] = r ;
// y_hat segment-sum via LDS (batch sorted -> block spans few graphs).
// ---------------------------------------------------------------------------
__global__ __launch_bounds__(256) void k_out(const float* __restrict__ d,
                                             const float* __restrict__ racc8,
                                             const int* __restrict__ batch,
                                             const float* __restrict__ eps1,
                                             const float* __restrict__ bc1,
                                             float* __restrict__ out) {
    __shared__ float acc[N_GRAPHS];
    int n0 = blockIdx.x * 256;
    int n  = n0 + threadIdx.x;
    int nlast = min(n0 + 255, N_NODES - 1);
    int g0 = batch[n0];
    int g1 = batch[nlast];
    for (int i = g0 + threadIdx.x; i <= g1; i += 256) acc[i] = 0.f;
    __syncthreads();
    if (n < N_NODES) {
        float r = (1.0f + eps1[0]) * d[n] + bc1[0];
#pragma unroll
        for (int c = 0; c < NCOPY; ++c) r += racc8[(size_t)c * N_NODES + n];
        out[N_GRAPHS + n] = r;
        atomicAdd(&acc[batch[n]], r);
    }
    __syncthreads();
    for (int i = g0 + threadIdx.x; i <= g1; i += 256) {
        float v = acc[i];
        if (v != 0.f) atomicAdd(&out[i], v);
    }
}

// ---------------------------------------------------------------------------
extern "C" void kernel_launch(void* const* d_in, const int* in_sizes, int n_in,
                              void* d_out, int out_size, void* d_ws, size_t ws_size,
                              hipStream_t stream) {
    const int*   x_idx = (const int*)d_in[0];
    const int*   esrc  = (const int*)d_in[1];
    const int*   edst  = (const int*)d_in[2];
    const int*   batch = (const int*)d_in[3];
    const float* embed = (const float*)d_in[4];
    const float* eps0  = (const float*)d_in[5];
    const float* w1_0  = (const float*)d_in[6];
    const float* b1_0  = (const float*)d_in[7];
    const float* w2_0  = (const float*)d_in[8];
    const float* b2_0  = (const float*)d_in[9];
    const float* eps1  = (const float*)d_in[10];
    const float* w1_1  = (const float*)d_in[11];
    const float* b1_1  = (const float*)d_in[12];
    const float* w2_1  = (const float*)d_in[13];
    const float* b2_1  = (const float*)d_in[14];

    float* out = (float*)d_out;

    // workspace layout: [counts | racc8 | d | Wc0 | bc0 | wc1 | bc1 | EW]
    int*   counts = (int*)d_ws;                                  // N*28 ints
    float* racc8  = (float*)(counts + (size_t)N_NODES * VOCAB);  // 8*N
    float* d      = racc8 + (size_t)NCOPY * N_NODES;             // N
    float* Wc0    = d + N_NODES;                                 // 128*128
    float* bc0    = Wc0 + HIDDEN * HIDDEN;                       // 128
    float* wc1    = bc0 + HIDDEN;                                // 128
    float* bc1    = wc1 + HIDDEN;                                // 1
    float* EW     = bc1 + 1;                                     // 28*128

    const int nEdgeBlocks   = (N_EDGES + 255) / 256;             // 6250
    const int nLayer0Blocks = (N_NODES + 4 * NPW - 1) / (4 * NPW); // 1563
    const int nOutBlocks    = (N_NODES + 255) / 256;             // 391

    // zero y_hat, counts, racc8 (counts+racc8 contiguous: (N*28+8*N)/4 int4)
    k_zero_f<<<(N_GRAPHS + 255) / 256, 256, 0, stream>>>(out, N_GRAPHS);
    {
        int n4 = (N_NODES * VOCAB + NCOPY * N_NODES) / 4;        // 900000
        k_zero_i4<<<(n4 + 255) / 256, 256, 0, stream>>>((int4*)counts, n4);
    }

    // fold weights: Wc0, bc0, wc1, bc1 ; then EW = embed @ Wc0
    k_prep<<<65, 256, 0, stream>>>(w1_0, w2_0, b1_0, b2_0, w1_1, b1_1, w2_1, b2_1,
                                   Wc0, bc0, wc1, bc1);
    k_prep2<<<(VOCAB * HIDDEN + 255) / 256, 256, 0, stream>>>(embed, Wc0, EW);

    // neighbor vocab histogram per node
    k_count<<<nEdgeBlocks, 256, 0, stream>>>(esrc, edst, x_idx, counts);

    // layer 0 + dot(wc1): d[n]
    k_layer0<<<nLayer0Blocks, 256, 0, stream>>>(x_idx, counts, EW, bc0, wc1, eps0, d);

    // layer 1 aggregation in scalar space, XCD-privatized
    k_dscatter<<<nEdgeBlocks, 256, 0, stream>>>(esrc, edst, d, racc8);

    // outputs: x and y_hat (reduce the 8 racc copies here)
    k_out<<<nOutBlocks, 256, 0, stream>>>(d, racc8, batch, eps1, bc1, out);
}

// Round 6
// 240.986 us; speedup vs baseline: 23.5747x; 1.2172x over previous
//
#include <hip/hip_runtime.h>

#define N_NODES  100000
#define N_EDGES  1600000
#define HIDDEN   128
#define N_GRAPHS 2048
#define VOCAB    28
#define NB       196        // node buckets of 512 (196*512 = 100352)
#define CAP      10000      // per-bucket edge capacity (E[cnt]=8163, sigma~90)
#define EPB      6250       // edges per binning block (256 blocks * 6250 = 1.6M exact)
#define EPT      25         // ceil(6250/256) edges per thread

// ---------------------------------------------------------------------------
// k_init: zero y_hat (2048) and the 256-entry bucket cursor array.
// grid 9*256 = 2304 threads.
// ---------------------------------------------------------------------------
__global__ void k_init(float* __restrict__ out, int* __restrict__ gcursor) {
    int i = blockIdx.x * blockDim.x + threadIdx.x;
    if (i < N_GRAPHS) out[i] = 0.0f;
    else if (i < N_GRAPHS + 256) gcursor[i - N_GRAPHS] = 0;
}

// ---------------------------------------------------------------------------
// k_prep: fold each layer's two linears into one.
// ---------------------------------------------------------------------------
__global__ __launch_bounds__(256) void k_prep(const float* __restrict__ w1_0,
                                              const float* __restrict__ w2_0,
                                              const float* __restrict__ b1_0,
                                              const float* __restrict__ b2_0,
                                              const float* __restrict__ w1_1,
                                              const float* __restrict__ b1_1,
                                              const float* __restrict__ w2_1,
                                              const float* __restrict__ b2_1,
                                              float* __restrict__ Wc0,
                                              float* __restrict__ bc0,
                                              float* __restrict__ wc1,
                                              float* __restrict__ bc1) {
    int t = threadIdx.x;
    if (blockIdx.x < 64) {
        int g = blockIdx.x * 256 + t;
        int i = g >> 7, j = g & 127;
        float s = 0.f;
#pragma unroll 8
        for (int k = 0; k < HIDDEN; ++k)
            s += w1_0[i * HIDDEN + k] * w2_0[k * HIDDEN + j];
        Wc0[g] = s;
    } else {
        if (t < 128) {
            float s = 0.f;
#pragma unroll 8
            for (int k = 0; k < HIDDEN; ++k)
                s += b1_0[k] * w2_0[k * HIDDEN + t];
            bc0[t] = s + b2_0[t];
            if (t == 0) {
                float q = 0.f;
                for (int k = 0; k < HIDDEN; ++k) q += b1_1[k] * w2_1[k];
                bc1[0] = q + b2_1[0];
            }
        } else {
            int i = t - 128;
            float s = 0.f;
#pragma unroll 8
            for (int k = 0; k < HIDDEN; ++k)
                s += w1_1[i * HIDDEN + k] * w2_1[k];
            wc1[i] = s;
        }
    }
}

// ---------------------------------------------------------------------------
// k_prep2: EW = embed @ Wc0   [28,128]
// ---------------------------------------------------------------------------
__global__ __launch_bounds__(256) void k_prep2(const float* __restrict__ embed,
                                               const float* __restrict__ Wc0,
                                               float* __restrict__ EW) {
    int g = blockIdx.x * 256 + threadIdx.x;
    if (g >= VOCAB * HIDDEN) return;
    int i = g >> 7, j = g & 127;
    float s = 0.f;
#pragma unroll 8
    for (int k = 0; k < HIDDEN; ++k)
        s += embed[i * HIDDEN + k] * Wc0[k * HIDDEN + j];
    EW[g] = s;
}

// ---------------------------------------------------------------------------
// k_bin: LDS multisplit of edges into NB dst-buckets.
// packed edge: (dst&511)<<22 | x_idx[src]<<17 | src   (31 bits)
// Per block: LDS histogram -> per-bucket chunk allocation via gcursor
// atomics (196/block) -> LDS-staged placement -> semi-coalesced global
// writes (runs of ~32 per bucket).
// ---------------------------------------------------------------------------
__global__ __launch_bounds__(256) void k_bin(const int* __restrict__ esrc,
                                             const int* __restrict__ edst,
                                             const int* __restrict__ x_idx,
                                             unsigned* __restrict__ binned,
                                             int* __restrict__ gcursor) {
    __shared__ int hist[256];
    __shared__ int scanbuf[256];
    __shared__ int lbase[256];
    __shared__ int lcur[256];
    __shared__ int gbase[256];
    __shared__ unsigned stage[EPB];
    __shared__ int tgt[EPB];

    const int tid = threadIdx.x;
    hist[tid] = 0;
    lcur[tid] = 0;
    __syncthreads();

    unsigned mypk[EPT];
    short    myb[EPT];
#pragma unroll
    for (int i = 0; i < EPT; ++i) {
        int idx = i * 256 + tid;
        myb[i] = -1;
        if (idx < EPB) {
            int e   = blockIdx.x * EPB + idx;
            int dst = edst[e];
            int src = esrc[e];
            int b   = dst >> 9;
            int dl  = dst & 511;
            int vix = x_idx[src];
            mypk[i] = ((unsigned)dl << 22) | ((unsigned)vix << 17) | (unsigned)src;
            myb[i]  = (short)b;
            atomicAdd(&hist[b], 1);
        }
    }
    __syncthreads();

    // exclusive scan of hist -> lbase; allocate global chunks
    int v = hist[tid];
    scanbuf[tid] = v;
    __syncthreads();
    for (int off = 1; off < 256; off <<= 1) {
        int x = (tid >= off) ? scanbuf[tid - off] : 0;
        __syncthreads();
        scanbuf[tid] += x;
        __syncthreads();
    }
    lbase[tid] = scanbuf[tid] - v;
    if (tid < NB) gbase[tid] = (v > 0) ? atomicAdd(&gcursor[tid], v) : 0;
    __syncthreads();

    // place into LDS in bucket-sorted order, record global targets
#pragma unroll
    for (int i = 0; i < EPT; ++i) {
        if (myb[i] >= 0) {
            int b   = myb[i];
            int pos = lbase[b] + atomicAdd(&lcur[b], 1);
            stage[pos] = mypk[i];
            tgt[pos]   = b * CAP + gbase[b] + (pos - lbase[b]);
        }
    }
    __syncthreads();

    // copy out: consecutive i -> consecutive targets within each bucket run
    for (int i = tid; i < EPB; i += 256)
        binned[tgt[i]] = stage[i];
}

// ---------------------------------------------------------------------------
// k_layerA: per (bucket b, half h) block of 256 nodes:
//   1) LDS vocab histogram of the bucket's in-edges (LDS atomics)
//   2) d[n] = dot(relu((1+eps0)*EW[xi] + sum_v cnt[v]*EW[v] + bc0), wc1)
// EW (14 KB) + counts (28.7 KB) in LDS. One wave per node group of 64.
// ---------------------------------------------------------------------------
__global__ __launch_bounds__(256) void k_layerA(const unsigned* __restrict__ binned,
                                                const int* __restrict__ gcursor,
                                                const int* __restrict__ x_idx,
                                                const float* __restrict__ EW,
                                                const float* __restrict__ bc0,
                                                const float* __restrict__ wc1,
                                                const float* __restrict__ eps0,
                                                float* __restrict__ d) {
    __shared__ __align__(16) float ew[VOCAB * HIDDEN];
    __shared__ float sbc0[HIDDEN];
    __shared__ float swc1[HIDDEN];
    __shared__ __align__(16) int lcnt[256 * VOCAB];

    const int tid = threadIdx.x;
    const int b   = blockIdx.x >> 1;
    const int h   = blockIdx.x & 1;

    for (int i = tid; i < VOCAB * HIDDEN; i += 256) ew[i] = EW[i];
    for (int i = tid; i < HIDDEN; i += 256) { sbc0[i] = bc0[i]; swc1[i] = wc1[i]; }
    for (int i = tid; i < 256 * VOCAB; i += 256) lcnt[i] = 0;
    __syncthreads();

    const int cnt = gcursor[b];
    const unsigned* bp = binned + (size_t)b * CAP;
    for (int i = tid; i < cnt; i += 256) {
        unsigned pk = bp[i];
        int dl = pk >> 22;
        if ((dl >> 8) == h)
            atomicAdd(&lcnt[(dl & 255) * VOCAB + ((pk >> 17) & 31)], 1);
    }
    __syncthreads();

    const int wave = tid >> 6, lane = tid & 63;
    const float s = 1.0f + eps0[0];
    const float wlo = swc1[lane], whi = swc1[lane + 64];
    const float blo = sbc0[lane], bhi = sbc0[lane + 64];

#pragma unroll 1
    for (int j = 0; j < 64; ++j) {
        int nl = wave * 64 + j;
        int n  = b * 512 + h * 256 + nl;
        if (n >= N_NODES) continue;

        int xi = x_idx[n];
        float a0 = s * ew[xi * HIDDEN + lane];
        float a1 = s * ew[xi * HIDDEN + lane + 64];

        const int4* cp = reinterpret_cast<const int4*>(&lcnt[nl * VOCAB]);
        int4 c[7];
#pragma unroll
        for (int q = 0; q < 7; ++q) c[q] = cp[q];

#define TERM(cc, v)                                             \
        if (cc) {                                               \
            float f = (float)(cc);                              \
            a0 += f * ew[(v) * HIDDEN + lane];                  \
            a1 += f * ew[(v) * HIDDEN + lane + 64];             \
        }
        TERM(c[0].x, 0)  TERM(c[0].y, 1)  TERM(c[0].z, 2)  TERM(c[0].w, 3)
        TERM(c[1].x, 4)  TERM(c[1].y, 5)  TERM(c[1].z, 6)  TERM(c[1].w, 7)
        TERM(c[2].x, 8)  TERM(c[2].y, 9)  TERM(c[2].z, 10) TERM(c[2].w, 11)
        TERM(c[3].x, 12) TERM(c[3].y, 13) TERM(c[3].z, 14) TERM(c[3].w, 15)
        TERM(c[4].x, 16) TERM(c[4].y, 17) TERM(c[4].z, 18) TERM(c[4].w, 19)
        TERM(c[5].x, 20) TERM(c[5].y, 21) TERM(c[5].z, 22) TERM(c[5].w, 23)
        TERM(c[6].x, 24) TERM(c[6].y, 25) TERM(c[6].z, 26) TERM(c[6].w, 27)
#undef TERM

        a0 = fmaxf(a0 + blo, 0.f);
        a1 = fmaxf(a1 + bhi, 0.f);
        float t = a0 * wlo + a1 * whi;
#pragma unroll
        for (int off = 32; off >= 1; off >>= 1) t += __shfl_xor(t, off, 64);
        if (lane == 0) d[n] = t;
    }
}

// ---------------------------------------------------------------------------
// k_B2: per bucket: racc in LDS (ds float atomics) from d[src] gathers
// (d = 400 KB, L2-resident). Fused output: x write + batch segment-sum.
// ---------------------------------------------------------------------------
__global__ __launch_bounds__(512) void k_B2(const unsigned* __restrict__ binned,
                                            const int* __restrict__ gcursor,
                                            const float* __restrict__ d,
                                            const int* __restrict__ batch,
                                            const float* __restrict__ eps1,
                                            const float* __restrict__ bc1,
                                            float* __restrict__ out) {
    __shared__ float racc[512];
    __shared__ float gacc[N_GRAPHS];

    const int tid = threadIdx.x;
    const int b   = blockIdx.x;
    const int n0  = b * 512;
    const int nlast = min(n0 + 511, N_NODES - 1);

    racc[tid] = 0.f;
    const int g0 = batch[n0];
    const int g1 = batch[nlast];
    for (int g = g0 + tid; g <= g1; g += 512) gacc[g] = 0.f;
    __syncthreads();

    const int cnt = gcursor[b];
    const unsigned* bp = binned + (size_t)b * CAP;
    for (int i = tid; i < cnt; i += 512) {
        unsigned pk = bp[i];
        atomicAdd(&racc[pk >> 22], d[pk & 0x1FFFFu]);
    }
    __syncthreads();

    int n = n0 + tid;
    if (n < N_NODES) {
        float r = (1.0f + eps1[0]) * d[n] + racc[tid] + bc1[0];
        out[N_GRAPHS + n] = r;
        atomicAdd(&gacc[batch[n]], r);
    }
    __syncthreads();
    for (int g = g0 + tid; g <= g1; g += 512) {
        float v = gacc[g];
        if (v != 0.f) atomicAdd(&out[g], v);
    }
}

// ---------------------------------------------------------------------------
extern "C" void kernel_launch(void* const* d_in, const int* in_sizes, int n_in,
                              void* d_out, int out_size, void* d_ws, size_t ws_size,
                              hipStream_t stream) {
    const int*   x_idx = (const int*)d_in[0];
    const int*   esrc  = (const int*)d_in[1];
    const int*   edst  = (const int*)d_in[2];
    const int*   batch = (const int*)d_in[3];
    const float* embed = (const float*)d_in[4];
    const float* eps0  = (const float*)d_in[5];
    const float* w1_0  = (const float*)d_in[6];
    const float* b1_0  = (const float*)d_in[7];
    const float* w2_0  = (const float*)d_in[8];
    const float* b2_0  = (const float*)d_in[9];
    const float* eps1  = (const float*)d_in[10];
    const float* w1_1  = (const float*)d_in[11];
    const float* b1_1  = (const float*)d_in[12];
    const float* w2_1  = (const float*)d_in[13];
    const float* b2_1  = (const float*)d_in[14];

    float* out = (float*)d_out;

    // workspace: [gcursor(256) | binned(NB*CAP) | d(N) | Wc0 | bc0 | wc1 | bc1 | EW]
    int*      gcursor = (int*)d_ws;                               // 256
    unsigned* binned  = (unsigned*)(gcursor + 256);               // NB*CAP
    float*    d       = (float*)(binned + (size_t)NB * CAP);      // N
    float*    Wc0     = d + N_NODES;                              // 128*128
    float*    bc0     = Wc0 + HIDDEN * HIDDEN;                    // 128
    float*    wc1     = bc0 + HIDDEN;                             // 128
    float*    bc1     = wc1 + HIDDEN;                             // 1
    float*    EW      = bc1 + 1;                                  // 28*128

    // init: y_hat + gcursor
    k_init<<<9, 256, 0, stream>>>(out, gcursor);

    // fold weights, then EW
    k_prep<<<65, 256, 0, stream>>>(w1_0, w2_0, b1_0, b2_0, w1_1, b1_1, w2_1, b2_1,
                                   Wc0, bc0, wc1, bc1);
    k_prep2<<<(VOCAB * HIDDEN + 255) / 256, 256, 0, stream>>>(embed, Wc0, EW);

    // bin edges by dst bucket (256 blocks * 6250 edges = 1.6M exact)
    k_bin<<<256, 256, 0, stream>>>(esrc, edst, x_idx, binned, gcursor);

    // layer 0 (+dot wc1): per bucket-half, LDS histogram + LDS EW
    k_layerA<<<NB * 2, 256, 0, stream>>>(binned, gcursor, x_idx, EW, bc0, wc1, eps0, d);

    // layer 1 aggregation in LDS + fused outputs
    k_B2<<<NB, 512, 0, stream>>>(binned, gcursor, d, batch, eps1, bc1, out);
}

// Round 7
// 174.698 us; speedup vs baseline: 32.5200x; 1.3794x over previous
//
#include <hip/hip_runtime.h>

#define N_NODES  100000
#define N_EDGES  1600000
#define HIDDEN   128
#define N_GRAPHS 2048
#define VOCAB    28
#define NB       196        // node buckets of 512 (196*512 = 100352)
#define CAP      10000      // per-bucket edge capacity (E[cnt]=8163, sigma~90)
#define EPB      6250       // edges per binning block (256 blocks * 6250 = 1.6M exact)
#define EPT      25         // ceil(6250/256) edges per thread
#define EWP      132        // padded LDS stride for ew (xi -> distinct banks)
#define CSTR     29         // lcnt stride (gcd(29,32)=1 -> conflict-free lane reads)

// ---------------------------------------------------------------------------
// k_init: zero y_hat (2048) and the 256-entry bucket cursor array.
// ---------------------------------------------------------------------------
__global__ void k_init(float* __restrict__ out, int* __restrict__ gcursor) {
    int i = blockIdx.x * blockDim.x + threadIdx.x;
    if (i < N_GRAPHS) out[i] = 0.0f;
    else if (i < N_GRAPHS + 256) gcursor[i - N_GRAPHS] = 0;
}

// ---------------------------------------------------------------------------
// k_prep: fold each layer's two linears into one.
// ---------------------------------------------------------------------------
__global__ __launch_bounds__(256) void k_prep(const float* __restrict__ w1_0,
                                              const float* __restrict__ w2_0,
                                              const float* __restrict__ b1_0,
                                              const float* __restrict__ b2_0,
                                              const float* __restrict__ w1_1,
                                              const float* __restrict__ b1_1,
                                              const float* __restrict__ w2_1,
                                              const float* __restrict__ b2_1,
                                              float* __restrict__ Wc0,
                                              float* __restrict__ bc0,
                                              float* __restrict__ wc1,
                                              float* __restrict__ bc1) {
    int t = threadIdx.x;
    if (blockIdx.x < 64) {
        int g = blockIdx.x * 256 + t;
        int i = g >> 7, j = g & 127;
        float s = 0.f;
#pragma unroll 8
        for (int k = 0; k < HIDDEN; ++k)
            s += w1_0[i * HIDDEN + k] * w2_0[k * HIDDEN + j];
        Wc0[g] = s;
    } else {
        if (t < 128) {
            float s = 0.f;
#pragma unroll 8
            for (int k = 0; k < HIDDEN; ++k)
                s += b1_0[k] * w2_0[k * HIDDEN + t];
            bc0[t] = s + b2_0[t];
            if (t == 0) {
                float q = 0.f;
                for (int k = 0; k < HIDDEN; ++k) q += b1_1[k] * w2_1[k];
                bc1[0] = q + b2_1[0];
            }
        } else {
            int i = t - 128;
            float s = 0.f;
#pragma unroll 8
            for (int k = 0; k < HIDDEN; ++k)
                s += w1_1[i * HIDDEN + k] * w2_1[k];
            wc1[i] = s;
        }
    }
}

// ---------------------------------------------------------------------------
// k_prep2: EW = embed @ Wc0   [28,128]
// ---------------------------------------------------------------------------
__global__ __launch_bounds__(256) void k_prep2(const float* __restrict__ embed,
                                               const float* __restrict__ Wc0,
                                               float* __restrict__ EW) {
    int g = blockIdx.x * 256 + threadIdx.x;
    if (g >= VOCAB * HIDDEN) return;
    int i = g >> 7, j = g & 127;
    float s = 0.f;
#pragma unroll 8
    for (int k = 0; k < HIDDEN; ++k)
        s += embed[i * HIDDEN + k] * Wc0[k * HIDDEN + j];
    EW[g] = s;
}

// ---------------------------------------------------------------------------
// k_bin: LDS multisplit of edges into NB dst-buckets.
// packed edge: (dst&511)<<22 | x_idx[src]<<17 | src   (31 bits)
// ---------------------------------------------------------------------------
__global__ __launch_bounds__(256) void k_bin(const int* __restrict__ esrc,
                                             const int* __restrict__ edst,
                                             const int* __restrict__ x_idx,
                                             unsigned* __restrict__ binned,
                                             int* __restrict__ gcursor) {
    __shared__ int hist[256];
    __shared__ int scanbuf[256];
    __shared__ int lbase[256];
    __shared__ int lcur[256];
    __shared__ int gbase[256];
    __shared__ unsigned stage[EPB];
    __shared__ int tgt[EPB];

    const int tid = threadIdx.x;
    hist[tid] = 0;
    lcur[tid] = 0;
    __syncthreads();

    unsigned mypk[EPT];
    short    myb[EPT];
#pragma unroll
    for (int i = 0; i < EPT; ++i) {
        int idx = i * 256 + tid;
        myb[i] = -1;
        if (idx < EPB) {
            int e   = blockIdx.x * EPB + idx;
            int dst = edst[e];
            int src = esrc[e];
            int b   = dst >> 9;
            int dl  = dst & 511;
            int vix = x_idx[src];
            mypk[i] = ((unsigned)dl << 22) | ((unsigned)vix << 17) | (unsigned)src;
            myb[i]  = (short)b;
            atomicAdd(&hist[b], 1);
        }
    }
    __syncthreads();

    int v = hist[tid];
    scanbuf[tid] = v;
    __syncthreads();
    for (int off = 1; off < 256; off <<= 1) {
        int x = (tid >= off) ? scanbuf[tid - off] : 0;
        __syncthreads();
        scanbuf[tid] += x;
        __syncthreads();
    }
    lbase[tid] = scanbuf[tid] - v;
    if (tid < NB) gbase[tid] = (v > 0) ? atomicAdd(&gcursor[tid], v) : 0;
    __syncthreads();

#pragma unroll
    for (int i = 0; i < EPT; ++i) {
        if (myb[i] >= 0) {
            int b   = myb[i];
            int pos = lbase[b] + atomicAdd(&lcur[b], 1);
            stage[pos] = mypk[i];
            tgt[pos]   = b * CAP + gbase[b] + (pos - lbase[b]);
        }
    }
    __syncthreads();

    for (int i = tid; i < EPB; i += 256)
        binned[tgt[i]] = stage[i];
}

// ---------------------------------------------------------------------------
// k_layerA: per (bucket b, half h) block of 256 nodes:
//   1) LDS vocab histogram of the bucket-half's in-edges
//   2) lane = node: counts -> 28 float VGPRs; serial loop over 32 float4
//      feature groups with EW read via WAVE-UNIFORM global loads (s_load) and
//      the per-lane xi self-term from a bank-padded LDS copy of EW.
//   d[n] = dot(relu((1+eps0)*EW[xi] + sum_v cnt_v*EW[v] + bc0), wc1)
// No cross-lane reduction; d writes coalesced.
// ---------------------------------------------------------------------------
__global__ __launch_bounds__(256) void k_layerA(const unsigned* __restrict__ binned,
                                                const int* __restrict__ gcursor,
                                                const int* __restrict__ x_idx,
                                                const float* __restrict__ EW,
                                                const float* __restrict__ bc0,
                                                const float* __restrict__ wc1,
                                                const float* __restrict__ eps0,
                                                float* __restrict__ d) {
    __shared__ __align__(16) float ewp[VOCAB * EWP];   // padded: xi -> distinct banks
    __shared__ int lcnt[256 * CSTR];

    const int tid = threadIdx.x;
    const int b   = blockIdx.x >> 1;
    const int h   = blockIdx.x & 1;

    for (int i = tid; i < VOCAB * HIDDEN; i += 256) {
        int v = i >> 7, f = i & 127;
        ewp[v * EWP + f] = EW[i];
    }
    for (int i = tid; i < 256 * CSTR; i += 256) lcnt[i] = 0;
    __syncthreads();

    const int cnt = gcursor[b];
    const unsigned* bp = binned + (size_t)b * CAP;
    for (int i = tid; i < cnt; i += 256) {
        unsigned pk = bp[i];
        int dl = pk >> 22;
        if ((dl >> 8) == h)
            atomicAdd(&lcnt[(dl & 255) * CSTR + ((pk >> 17) & 31)], 1);
    }
    __syncthreads();

    const int nl = tid;                 // node-local 0..255 (lane = node)
    const int n  = b * 512 + h * 256 + nl;

    // per-lane counts -> float regs (stride 29: conflict-free)
    float cf[VOCAB];
#pragma unroll
    for (int v = 0; v < VOCAB; ++v) cf[v] = (float)lcnt[nl * CSTR + v];

    const float s  = 1.0f + eps0[0];
    const int   xi = (n < N_NODES) ? x_idx[n] : 0;
    const float* exr = &ewp[xi * EWP];

    const float4* EW4 = reinterpret_cast<const float4*>(EW);   // [v][32] f4, uniform
    const float4* b04 = reinterpret_cast<const float4*>(bc0);
    const float4* w14 = reinterpret_cast<const float4*>(wc1);

    float dacc = 0.f;
#pragma unroll 1
    for (int f4 = 0; f4 < 32; ++f4) {
        float4 a = b04[f4];                                    // uniform -> s_load
        float4 ex = *reinterpret_cast<const float4*>(exr + f4 * 4);  // LDS b128
        a.x += s * ex.x; a.y += s * ex.y; a.z += s * ex.z; a.w += s * ex.w;
#pragma unroll
        for (int v = 0; v < VOCAB; ++v) {
            float4 e = EW4[v * 32 + f4];                       // uniform -> s_load_dwordx4
            a.x += cf[v] * e.x;
            a.y += cf[v] * e.y;
            a.z += cf[v] * e.z;
            a.w += cf[v] * e.w;
        }
        float4 w = w14[f4];                                    // uniform -> s_load
        dacc += fmaxf(a.x, 0.f) * w.x + fmaxf(a.y, 0.f) * w.y
              + fmaxf(a.z, 0.f) * w.z + fmaxf(a.w, 0.f) * w.w;
    }
    if (n < N_NODES) d[n] = dacc;
}

// ---------------------------------------------------------------------------
// k_B2: per bucket: racc in LDS (ds float atomics) from d[src] gathers.
// Fused output: x write + batch segment-sum.
// ---------------------------------------------------------------------------
__global__ __launch_bounds__(512) void k_B2(const unsigned* __restrict__ binned,
                                            const int* __restrict__ gcursor,
                                            const float* __restrict__ d,
                                            const int* __restrict__ batch,
                                            const float* __restrict__ eps1,
                                            const float* __restrict__ bc1,
                                            float* __restrict__ out) {
    __shared__ float racc[512];
    __shared__ float gacc[N_GRAPHS];

    const int tid = threadIdx.x;
    const int b   = blockIdx.x;
    const int n0  = b * 512;
    const int nlast = min(n0 + 511, N_NODES - 1);

    racc[tid] = 0.f;
    const int g0 = batch[n0];
    const int g1 = batch[nlast];
    for (int g = g0 + tid; g <= g1; g += 512) gacc[g] = 0.f;
    __syncthreads();

    const int cnt = gcursor[b];
    const unsigned* bp = binned + (size_t)b * CAP;
    for (int i = tid; i < cnt; i += 512) {
        unsigned pk = bp[i];
        atomicAdd(&racc[pk >> 22], d[pk & 0x1FFFFu]);
    }
    __syncthreads();

    int n = n0 + tid;
    if (n < N_NODES) {
        float r = (1.0f + eps1[0]) * d[n] + racc[tid] + bc1[0];
        out[N_GRAPHS + n] = r;
        atomicAdd(&gacc[batch[n]], r);
    }
    __syncthreads();
    for (int g = g0 + tid; g <= g1; g += 512) {
        float v = gacc[g];
        if (v != 0.f) atomicAdd(&out[g], v);
    }
}

// ---------------------------------------------------------------------------
extern "C" void kernel_launch(void* const* d_in, const int* in_sizes, int n_in,
                              void* d_out, int out_size, void* d_ws, size_t ws_size,
                              hipStream_t stream) {
    const int*   x_idx = (const int*)d_in[0];
    const int*   esrc  = (const int*)d_in[1];
    const int*   edst  = (const int*)d_in[2];
    const int*   batch = (const int*)d_in[3];
    const float* embed = (const float*)d_in[4];
    const float* eps0  = (const float*)d_in[5];
    const float* w1_0  = (const float*)d_in[6];
    const float* b1_0  = (const float*)d_in[7];
    const float* w2_0  = (const float*)d_in[8];
    const float* b2_0  = (const float*)d_in[9];
    const float* eps1  = (const float*)d_in[10];
    const float* w1_1  = (const float*)d_in[11];
    const float* b1_1  = (const float*)d_in[12];
    const float* w2_1  = (const float*)d_in[13];
    const float* b2_1  = (const float*)d_in[14];

    float* out = (float*)d_out;

    // workspace: [gcursor(256) | binned(NB*CAP) | d(N) | Wc0 | bc0 | wc1 | bc1 | EW]
    int*      gcursor = (int*)d_ws;                               // 256
    unsigned* binned  = (unsigned*)(gcursor + 256);               // NB*CAP
    float*    d       = (float*)(binned + (size_t)NB * CAP);      // N
    float*    Wc0     = d + N_NODES;                              // 128*128
    float*    bc0     = Wc0 + HIDDEN * HIDDEN;                    // 128
    float*    wc1     = bc0 + HIDDEN;                             // 128
    float*    bc1     = wc1 + HIDDEN;                             // 1
    float*    EW      = bc1 + 1;                                  // 28*128

    // init: y_hat + gcursor
    k_init<<<9, 256, 0, stream>>>(out, gcursor);

    // fold weights, then EW
    k_prep<<<65, 256, 0, stream>>>(w1_0, w2_0, b1_0, b2_0, w1_1, b1_1, w2_1, b2_1,
                                   Wc0, bc0, wc1, bc1);
    k_prep2<<<(VOCAB * HIDDEN + 255) / 256, 256, 0, stream>>>(embed, Wc0, EW);

    // bin edges by dst bucket
    k_bin<<<256, 256, 0, stream>>>(esrc, edst, x_idx, binned, gcursor);

    // layer 0 (+dot wc1): lane=node, scalar-operand FMA loop
    k_layerA<<<NB * 2, 256, 0, stream>>>(binned, gcursor, x_idx, EW, bc0, wc1, eps0, d);

    // layer 1 aggregation in LDS + fused outputs
    k_B2<<<NB, 512, 0, stream>>>(binned, gcursor, d, batch, eps1, bc1, out);
}